// Round 14
// baseline (104.120 us; speedup 1.0000x reference)
//
#include <hip/hip_runtime.h>
#include <math.h>

#define H 256
#define W 256
#define HW (H * W)
#define CH 24
#define NK 63
#define KSTEPS 25       // K = 25 taps * 32 (24 ch + 8 zero-pad in A-frags)
#define NE 257          // table dwords per channel (pairs of 258 samples)
#define TBLN (CH * NE)  // 6168 dwords per table
#define T3S 26          // t3 per-pixel stride in floats

typedef short v8s __attribute__((ext_vector_type(8)));
typedef short v4s __attribute__((ext_vector_type(4)));
typedef float v4f __attribute__((ext_vector_type(4)));

// ---------------- bf16 helper ----------------------------------------------------
__device__ __forceinline__ short f2bf(float v) {
    unsigned u = __float_as_uint(v);
    u += 0x7fff + ((u >> 16) & 1);
    return (short)(u >> 16);
}

// ---------------- table lookup (global, L1-resident) ------------------------------
struct TblCtx { float off, invh; };
__device__ __forceinline__ TblCtx make_tctx(const float* __restrict__ mean) {
    TblCtx c;
    float lo = mean[0] - 12.f;
    float hi = mean[NK - 1] + 12.f;
    c.invh = 257.f / (hi - lo);
    c.off  = -lo * c.invh;
    return c;
}
__device__ __forceinline__ float tbl_eval(const unsigned* __restrict__ tbl, int ch,
                                          float v, const TblCtx& c) {
    float t = fmaf(v, c.invh, c.off);
    t = fminf(fmaxf(t, 0.f), 256.999f);
    float fi = floorf(t);
    float fr = t - fi;
    unsigned u = tbl[ch * NE + (int)fi];        // global dword, L1-hit
    float a = __uint_as_float(u << 16);
    float b = __uint_as_float(u & 0xffff0000u);
    return fmaf(fr, b - a, a);
}

// ---------------- LDS union: 31.5 KB -> 4 blocks/CU --------------------------------
struct Smem {
    union {
        short t1[400 * 24 + 8];   // 20x20 rbf0(conv1) tile, ph1->ph2 (19216 B)
        float t3[144 * T3S];      // 12x12 rbf_der tile, ph3->ph4   (14976 B)
    } u1;
    union {
        float xs[576];            // 24x24 x window, ph1            (2304 B)
        short tbt[256 * 24 + 8];  // 16x16 rbf1(conv2) tile, ph2->ph3 (12304 B)
        float red[256];           // reduction buf, ph4
    } u2;
};

// ---------------- prep: norms, f0n/f0t, A-frag pack, RBF tables --------------------
// abuf: [mode 2][mtile 2][kstep 25][lane 64] v8s. k = tap*32 + c (c<24, pad=0).
// tables: tg[tt][ch][NE], tt: 0=rbf(aw0), 1=rbf(aw1), 2=rbf_der(aw0); exact 63-tap.
__global__ void k_prep(const float* __restrict__ f0, const float* __restrict__ f1,
                       const float* __restrict__ mean, const float* __restrict__ aw0,
                       const float* __restrict__ aw1,
                       float* __restrict__ f0n, float* __restrict__ f0t,
                       v8s* __restrict__ abuf, unsigned* __restrict__ tg) {
    __shared__ float red[256];
    int tid = threadIdx.x;
    float s1 = 0.f;
    for (int i = tid; i < 14400; i += 256) s1 += f1[i] * f1[i];
    red[tid] = s1; __syncthreads();
    for (int off = 128; off; off >>= 1) { if (tid < off) red[tid] += red[tid + off]; __syncthreads(); }
    float inv1 = 1.f / sqrtf(red[0]);
    __syncthreads();
    if (blockIdx.x == 0) {
        float s0 = 0.f;
        for (int i = tid; i < 600; i += 256) s0 += f0[i] * f0[i];
        red[tid] = s0; __syncthreads();
        for (int off = 128; off; off >>= 1) { if (tid < off) red[tid] += red[tid + off]; __syncthreads(); }
        float inv0 = 1.f / sqrtf(red[0]);
        for (int i = tid; i < 600; i += 256) {
            int c = i / 25, k = i % 25;
            f0n[i] = f0[i] * inv0;
            f0t[i] = f0[c * 25 + (24 - k)] * inv0;
        }
    }
    int gid = blockIdx.x * 256 + tid;      // 6400 jobs
    {
        int lane = gid & 63;
        int rest = gid >> 6;               // 0..99
        int s = rest % KSTEPS;
        int md = rest / KSTEPS;            // 0..3
        int mode = md >> 1, m = md & 1;
        int o = m * 16 + (lane & 15);
        v8s av;
        #pragma unroll
        for (int j = 0; j < 8; ++j) {
            int c = 8 * (lane >> 4) + j;
            float wv = 0.f;
            if (o < CH && c < CH) {
                wv = (mode == 0) ? f1[(o * CH + c) * 25 + s]
                                 : f1[(c * CH + o) * 25 + (24 - s)];
                wv *= inv1;
            }
            av[j] = f2bf(wv);
        }
        abuf[gid] = av;
    }
    float lo = mean[0] - 12.f;
    float hi = mean[NK - 1] + 12.f;
    float h  = (hi - lo) * (1.f / 257.f);
    for (int j = gid; j < 3 * TBLN; j += 6400) {
        int tt = j / TBLN;
        int rest = j - tt * TBLN;
        int ch = rest / NE;
        int i  = rest - ch * NE;
        const float* wr = ((tt == 1) ? aw1 : aw0) + ch * NK;
        float v0 = fmaf(h, (float)i, lo);
        float v1 = v0 + h;
        float s0 = 0.f, s1v = 0.f;
        for (int k = 0; k < NK; ++k) {
            float m = mean[k], wk = wr[k];
            float d0 = v0 - m, d1 = v1 - m;
            float e0 = __expf(d0 * d0 * -0.005f);
            float e1 = __expf(d1 * d1 * -0.005f);
            if (tt == 2) { e0 *= d0 * -0.01f; e1 *= d1 * -0.01f; }
            s0 = fmaf(e0, wk, s0);
            s1v = fmaf(e1, wk, s1v);
        }
        unsigned pb = ((unsigned)(unsigned short)f2bf(s1v) << 16)
                    | (unsigned)(unsigned short)f2bf(s0);
        tg[j] = pb;
    }
}

// ---------------- fused main: all 4 stages, intermediates in LDS -------------------
// 8x8 output tile, 1024 blocks, 4 blocks/CU (31.5 KB LDS, VGPR<=128).
__global__ __launch_bounds__(256, 4) void k_main(
        const float* __restrict__ x, const float* __restrict__ y,
        const float* __restrict__ f0n, const float* __restrict__ f0t,
        const v8s* __restrict__ abuf, const float* __restrict__ mean,
        const unsigned* __restrict__ T0g, const unsigned* __restrict__ T1g,
        const unsigned* __restrict__ TDg, const float* __restrict__ lamp,
        float* __restrict__ out) {
    __shared__ Smem sm;
    int tid = threadIdx.x;
    int x0 = (blockIdx.x & 31) * 8, y0 = (blockIdx.x >> 5) * 8;
    TblCtx ctx = make_tctx(mean);

    // stage: x window 24x24 at origin (y0-8, x0-8), clamped (= replication pad)
    for (int i = tid; i < 576; i += 256) {
        int r = (i * 2731) >> 16;          // i / 24
        int cL = i - r * 24;
        int gy = min(max(y0 + r - 8, 0), H - 1);
        int gx = min(max(x0 + cL - 8, 0), W - 1);
        sm.u2.xs[i] = x[gy * W + gx];
    }
    __syncthreads();

    // ---- phase 1: t1 = rbf0(conv1(x)) on 20x20 (origin y0-6, x0-6) ----
    // 1200 jobs = (og 0..2) x (px 0..399)
    #pragma unroll 1
    for (int j = tid; j < 1200; j += 256) {
        int og = (j * 164) >> 16;          // j / 400 (exact for j < 1200)
        int px = j - og * 400;
        int yi = (px * 3277) >> 16;        // px / 20
        int xi = px - yi * 20;
        int sy = min(max(y0 + yi - 6, 0), H - 1);
        int sx = min(max(x0 + xi - 6, 0), W - 1);
        int iy[5], ix[5];
        #pragma unroll
        for (int u = 0; u < 5; ++u) {
            iy[u] = min(max(sy + u - 2, 0), H - 1) - (y0 - 8);
            ix[u] = min(max(sx + u - 2, 0), W - 1) - (x0 - 8);
        }
        float in_[25];
        #pragma unroll
        for (int u = 0; u < 5; ++u)
            #pragma unroll
            for (int v = 0; v < 5; ++v) in_[u * 5 + v] = sm.u2.xs[iy[u] * 24 + ix[v]];
        v8s pk;
        #pragma unroll
        for (int oj = 0; oj < 8; ++oj) {
            int o = og * 8 + oj;
            float a = 0.f;
            #pragma unroll
            for (int k = 0; k < 25; ++k) a = fmaf(in_[k], f0n[o * 25 + k], a);
            pk[oj] = f2bf(tbl_eval(T0g, o, a, ctx));
        }
        *(v8s*)&sm.u1.t1[px * 24 + og * 8] = pk;
    }
    if (tid == 0) {   // tail pad: q=3 stray reads of last pixel stay in-bounds
        v8s z = {0,0,0,0,0,0,0,0};
        *(v8s*)&sm.u1.t1[9600] = z;
    }
    __syncthreads();

    // ---- phase 2: tbt = rbf1(conv2(t1)) on 16x16 (origin y0-4, x0-4), LDS only ----
    int lane = tid & 63, wv_ = tid >> 6;
    int p = lane & 15, q = lane >> 4;
    {
        v4f a0[4], a1[4];
        #pragma unroll
        for (int g = 0; g < 4; ++g) { a0[g] = (v4f){0.f,0.f,0.f,0.f}; a1[g] = (v4f){0.f,0.f,0.f,0.f}; }
        #pragma unroll
        for (int s = 0; s < KSTEPS; ++s) {
            const int u = s / 5, v = s % 5;            // compile-time
            v8s af0 = abuf[s * 64 + lane];
            v8s af1 = abuf[1600 + s * 64 + lane];
            #pragma unroll
            for (int g = 0; g < 4; ++g) {
                int row = wv_ * 4 + g;                 // wave owns 4 rows of 16
                v8s b = *(const v8s*)&sm.u1.t1[((row + u) * 20 + (p + v)) * 24 + q * 8];
                a0[g] = __builtin_amdgcn_mfma_f32_16x16x32_bf16(af0, b, a0[g], 0, 0, 0);
                a1[g] = __builtin_amdgcn_mfma_f32_16x16x32_bf16(af1, b, a1[g], 0, 0, 0);
            }
        }
        __syncthreads();   // t1 reads done everywhere? No: t1 read only above; but
                           // tbt overlays xs (dead since phase1) -> safe to write now.
        #pragma unroll
        for (int g = 0; g < 4; ++g) {
            int row = wv_ * 4 + g;
            int gy = y0 - 4 + row, gx = x0 - 4 + p;
            bool inimg = (gy >= 0 && gy < H && gx >= 0 && gx < W);
            v4s st;
            #pragma unroll
            for (int j = 0; j < 4; ++j)
                st[j] = inimg ? f2bf(tbl_eval(T1g, q * 4 + j, a0[g][j], ctx)) : (short)0;
            *(v4s*)&sm.u2.tbt[(row * 16 + p) * 24 + q * 4] = st;
            if (q < 2) {
                #pragma unroll
                for (int j = 0; j < 4; ++j)
                    st[j] = inimg ? f2bf(tbl_eval(T1g, 16 + q * 4 + j, a1[g][j], ctx)) : (short)0;
                *(v4s*)&sm.u2.tbt[(row * 16 + p) * 24 + 16 + q * 4] = st;
            }
        }
        if (tid == 0) {
            v8s z = {0,0,0,0,0,0,0,0};
            *(v8s*)&sm.u2.tbt[6144] = z;
        }
    }
    __syncthreads();

    // ---- phase 3: t3 = rbf'(convT2(tbt)) on 12x12 (origin y0-2, x0-2) ----
    // waves 0..2 own 3 N-tiles each (9 x 16 = 144 px); t3 overlays t1 (dead).
    if (wv_ < 3) {
        const v8s* ap = abuf + 3200;       // mode-1 fragments
        int base[3], frow[3], fcol[3];
        #pragma unroll
        for (int g = 0; g < 3; ++g) {
            int f = (wv_ * 3 + g) * 16 + p;
            int r_ = (f * 5462) >> 16;     // f / 12
            frow[g] = r_; fcol[g] = f - r_ * 12;
            base[g] = (r_ * 16 + fcol[g]) * 24 + q * 8;
        }
        v4f c0[3], c1[3];
        #pragma unroll
        for (int g = 0; g < 3; ++g) { c0[g] = (v4f){0.f,0.f,0.f,0.f}; c1[g] = (v4f){0.f,0.f,0.f,0.f}; }
        #pragma unroll
        for (int s = 0; s < KSTEPS; ++s) {
            const int off = ((s / 5) * 16 + (s % 5)) * 24;
            v8s af0 = ap[s * 64 + lane];
            v8s af1 = ap[1600 + s * 64 + lane];
            #pragma unroll
            for (int g = 0; g < 3; ++g) {
                v8s b = *(const v8s*)&sm.u2.tbt[base[g] + off];
                c0[g] = __builtin_amdgcn_mfma_f32_16x16x32_bf16(af0, b, c0[g], 0, 0, 0);
                c1[g] = __builtin_amdgcn_mfma_f32_16x16x32_bf16(af1, b, c1[g], 0, 0, 0);
            }
        }
        #pragma unroll
        for (int g = 0; g < 3; ++g) {
            int f = (wv_ * 3 + g) * 16 + p;
            int gy = y0 + frow[g] - 2, gx = x0 + fcol[g] - 2;
            bool inimg = (gy >= 0 && gy < H && gx >= 0 && gx < W);
            #pragma unroll
            for (int j = 0; j < 4; ++j)
                sm.u1.t3[f * T3S + q * 4 + j] =
                    inimg ? tbl_eval(TDg, q * 4 + j, c0[g][j], ctx) : 0.f;
            if (q < 2) {
                #pragma unroll
                for (int j = 0; j < 4; ++j)
                    sm.u1.t3[f * T3S + 16 + q * 4 + j] =
                        inimg ? tbl_eval(TDg, 16 + q * 4 + j, c1[g][j], ctx) : 0.f;
            }
        }
    }
    __syncthreads();

    // ---- phase 4: convT1 (24->1, pre-flipped f0t) + final combine ----
    int gq = __builtin_amdgcn_readfirstlane(tid >> 6);
    int px4 = tid & 63, pr = px4 >> 3, pc = px4 & 7;
    float a = 0.f;
    #pragma unroll 1
    for (int cp = 0; cp < 3; ++cp) {
        int c = gq * 6 + cp * 2;               // even -> 8B-aligned float2
        const float* fb0 = f0t + c * 25;
        const float* fb1 = f0t + (c + 1) * 25;
        #pragma unroll
        for (int u = 0; u < 5; ++u)
            #pragma unroll
            for (int v = 0; v < 5; ++v) {
                float2 tp = *(const float2*)&sm.u1.t3[((pr + u) * 12 + (pc + v)) * T3S + c];
                a = fmaf(tp.x, fb0[u * 5 + v], a);
                a = fmaf(tp.y, fb1[u * 5 + v], a);
            }
    }
    sm.u2.red[tid] = a;
    __syncthreads();
    if (tid < 64) {
        float tot = sm.u2.red[tid] + sm.u2.red[64 + tid]
                  + sm.u2.red[128 + tid] + sm.u2.red[192 + tid];
        int pix = (y0 + pr) * W + (x0 + pc);
        float elam = __expf(lamp[0]);
        float xv = x[pix], yv = y[pix];
        out[pix] = xv - (tot + elam * (xv - yv));
    }
}

extern "C" void kernel_launch(void* const* d_in, const int* in_sizes, int n_in,
                              void* d_out, int out_size, void* d_ws, size_t ws_size,
                              hipStream_t stream) {
    const float* x    = (const float*)d_in[0];
    const float* y    = (const float*)d_in[1];
    const float* f0   = (const float*)d_in[3];
    const float* f1   = (const float*)d_in[4];
    const float* aw0  = (const float*)d_in[5];
    const float* aw1  = (const float*)d_in[6];
    const float* mean = (const float*)d_in[7];
    const float* lamp = (const float*)d_in[8];
    float* out = (float*)d_out;

    float* w   = (float*)d_ws;
    float* f0n = w;                          // 600
    float* f0t = w + 640;                    // 600
    v8s*  abuf = (v8s*)(w + 1536);           // 6400*16B -> ends at w+27136
    unsigned* tg = (unsigned*)(w + 27136);   // 3*6168 dwords
    unsigned* T0g = tg;
    unsigned* T1g = tg + TBLN;
    unsigned* TDg = tg + 2 * TBLN;

    k_prep<<<25, 256, 0, stream>>>(f0, f1, mean, aw0, aw1, f0n, f0t, abuf, tg);
    k_main<<<1024, 256, 0, stream>>>(x, y, f0n, f0t, abuf, mean, T0g, T1g, TDg, lamp, out);
}